// Round 12
// baseline (11080.811 us; speedup 1.0000x reference)
//
#include <hip/hip_runtime.h>
#include <math.h>

#pragma clang fp contract(off)

// LTC network: B=32, T=128, IN=128, H=256, OUT=128, 5 RK4 steps/t, dt=0.01
// Round 12: bit-exact arithmetic (absmax 0.0 since R9). Structural perf fix:
//  - 256 thr/block, thread i computes BOTH dots (S,A) + elementwise for h_i.
//    4 waves/CU = 1 wave/SIMD -> 512-VGPR budget; amdgpu_waves_per_eu(1,1)
//    forces the allocator to plan for it. wr[192]+wa[192] register-resident.
//  - halves DS broadcast traffic (one h read feeds both chains);
//    removes the partA LDS exchange entirely.
//  - R11's 8-wave workgroup capped VGPR at 256 (2 waves/SIMD co-residency)
//    and the heuristic stuck at 128 -> w[] spilled; that was the bottleneck.
// Numerics (DO NOT TOUCH — bit-exact vs XLA-CPU golden):
//  dots: ascending-k __builtin_fmaf chain from 0.0; x/bias added after,
//  unfused; sigmoid = 1/(1+CephesExp(-z)) per GenerateVF32Exp; unfused RK4
//  elementwise; fp contract off file-wide.

#define Bn 32
#define Tn 128
#define INn 128
#define Hn 256
#define OUTn 128
#define NSTEPS 5

__device__ __forceinline__ float f32clip(float x, float lo, float hi) {
  float y = (x >= lo) ? x : lo;
  y = (y <= hi) ? y : hi;
  return (x == x) ? y : x;    // NaN propagates (safety; none occur)
}

// XLA CPU GenerateVF32Exp (Cephes expf), bit-exact reconstruction.
__device__ __forceinline__ float xla_expf(float x) {
  x = fminf(x, 88.3762626647950f);         // clamp high
  x = fmaxf(x, -88.3762626647949f);        // clamp low
  float fx = floorf(__builtin_fmaf(x, 1.44269504088896341f, 0.5f)); // fused
  float tmp = __fmul_rn(0.693359375f, fx);         // unfused Cody-Waite hi
  float z  = __fmul_rn(-2.12194440e-4f, fx);       // unfused Cody-Waite lo
  float r  = __fsub_rn(x, tmp);
  r = __fsub_rn(r, z);
  float r2 = __fmul_rn(r, r);
  float y = __builtin_fmaf(r, 1.9875691500e-4f, 1.3981999507e-3f);  // MulAdd
  y = __builtin_fmaf(y, r, 8.3334519073e-3f);
  y = __builtin_fmaf(y, r, 4.1665795894e-2f);
  y = __builtin_fmaf(y, r, 1.6666665459e-1f);
  y = __builtin_fmaf(y, r, 5.0000001201e-1f);
  y = __builtin_fmaf(y, r2, r);
  y = __fadd_rn(1.0f, y);
  int m = (int)fx;                          // FPToSI (fx integral)
  float s = __int_as_float((m + 127) << 23);
  return __fmul_rn(y, s);
}

// LogisticExpander: 1 / (1 + exp(-z))
__device__ __forceinline__ float xla_sigmoid(float zin) {
  float e = xla_expf(-zin);
  return 1.0f / __fadd_rn(1.0f, e);        // IEEE f32 div
}

__global__ __launch_bounds__(256) void k_prep(const float* __restrict__ W_in,
                                              const float* __restrict__ W_out,
                                              const float* __restrict__ W_rec,
                                              const float* __restrict__ W_adapt,
                                              float* __restrict__ W_inT,
                                              float* __restrict__ W_outT,
                                              float* __restrict__ W_recT,
                                              float* __restrict__ W_adaptT) {
  int idx = blockIdx.x * 256 + threadIdx.x;     // 768*256 = 196608
  if (idx < 32768) {            // W_in [256][128] -> W_inT[j][h]
    int h = idx >> 7, j = idx & 127;
    W_inT[j * Hn + h] = W_in[idx];
  } else if (idx < 65536) {     // W_out [128][256] -> W_outT[i][o]
    int k = idx - 32768; int o = k >> 8, i = k & 255;
    W_outT[i * OUTn + o] = W_out[k];
  } else if (idx < 131072) {    // W_rec [256][256] -> W_recT[c][r]
    int k = idx - 65536; int r = k >> 8, c = k & 255;
    W_recT[c * Hn + r] = W_rec[k];
  } else {                      // W_adapt -> W_adaptT[c][r]
    int k = idx - 131072; int r = k >> 8, c = k & 255;
    W_adaptT[c * Hn + r] = W_adapt[k];
  }
}

// emb[b,t,h] = (ascending-i fmaf chain, Eigen) x[b,t,:].W_in[h,:], then + b_in
__global__ __launch_bounds__(256) void k_embed(const float* __restrict__ xin,
                                               const float* __restrict__ W_inT,
                                               const float* __restrict__ b_in,
                                               float* __restrict__ emb) {
  __shared__ float xs[INn];
  int bt = blockIdx.x, h = threadIdx.x;
  if (h < INn) xs[h] = xin[bt * INn + h];
  __syncthreads();
  float d = 0.f;
  #pragma unroll
  for (int j = 0; j < INn; ++j)
    d = __builtin_fmaf(xs[j], W_inT[j * Hn + h], d);  // Eigen gebp chain
  emb[bt * Hn + h] = __fadd_rn(d, b_in[h]);           // + b_in separate op
}

__global__ __launch_bounds__(256, 1)
__attribute__((amdgpu_waves_per_eu(1, 1)))
void k_ltc(const float* __restrict__ W_recT,
           const float* __restrict__ W_adaptT,
           const float* __restrict__ tau,
           const float* __restrict__ emb,
           float* __restrict__ h_hist) {
  const int b = blockIdx.x;
  const int i = threadIdx.x;     // owns h_i: both dots + elementwise

  __shared__ __align__(16) float h_lds[Hn];

  float wr[192];
  float wa[192];
  #pragma unroll
  for (int m = 0; m < 192; ++m) wr[m] = W_recT[m * Hn + i];    // coalesced
  #pragma unroll
  for (int m = 0; m < 192; ++m) wa[m] = W_adaptT[m * Hn + i];  // coalesced
  #pragma unroll
  for (int m = 0; m < 192; ++m) asm volatile("" : "+v"(wr[m]));  // pin
  #pragma unroll
  for (int m = 0; m < 192; ++m) asm volatile("" : "+v"(wa[m]));  // pin
  const float* recTail   = W_recT + 192 * Hn;     // rows 192..255
  const float* adaptTail = W_adaptT + 192 * Hn;
  const float tau_i = tau[i];
  const float C_DT6 = (float)(0.01 / 6.0);  // f32(DT/6.0), weak-scalar cast
  float h = 0.f, hcur = 0.f, acc = 0.f;
  h_lds[i] = 0.f;
  __syncthreads();

  #pragma unroll 1
  for (int t = 0; t < Tn; ++t) {
    const float x = emb[(b * Tn + t) * Hn + i];
    #pragma unroll 1
    for (int s = 0; s < NSTEPS; ++s) {
      #pragma unroll 1
      for (int st = 0; st < 4; ++st) {
        // dots: ascending-j fmaf chains from 0 (Eigen gebp per-element chain).
        // One h broadcast (b128) feeds BOTH chains; per-element order unchanged.
        float dS = 0.f, dA = 0.f;
        const float4* h4 = reinterpret_cast<const float4*>(h_lds);
        #pragma unroll
        for (int j4 = 0; j4 < 48; ++j4) {           // j = 0..191 from VGPRs
          const float4 hv = h4[j4];
          dS = __builtin_fmaf(hv.x, wr[4*j4+0], dS);
          dS = __builtin_fmaf(hv.y, wr[4*j4+1], dS);
          dS = __builtin_fmaf(hv.z, wr[4*j4+2], dS);
          dS = __builtin_fmaf(hv.w, wr[4*j4+3], dS);
          dA = __builtin_fmaf(hv.x, wa[4*j4+0], dA);
          dA = __builtin_fmaf(hv.y, wa[4*j4+1], dA);
          dA = __builtin_fmaf(hv.z, wa[4*j4+2], dA);
          dA = __builtin_fmaf(hv.w, wa[4*j4+3], dA);
        }
        #pragma unroll
        for (int j4 = 48; j4 < 64; ++j4) {          // j = 192..255 from L2
          const float4 hv = h4[j4];
          const int jj = 4*j4 - 192;
          dS = __builtin_fmaf(hv.x, recTail[(jj+0) * Hn + i], dS);
          dS = __builtin_fmaf(hv.y, recTail[(jj+1) * Hn + i], dS);
          dS = __builtin_fmaf(hv.z, recTail[(jj+2) * Hn + i], dS);
          dS = __builtin_fmaf(hv.w, recTail[(jj+3) * Hn + i], dS);
          dA = __builtin_fmaf(hv.x, adaptTail[(jj+0) * Hn + i], dA);
          dA = __builtin_fmaf(hv.y, adaptTail[(jj+1) * Hn + i], dA);
          dA = __builtin_fmaf(hv.z, adaptTail[(jj+2) * Hn + i], dA);
          dA = __builtin_fmaf(hv.w, adaptTail[(jj+3) * Hn + i], dA);
        }
        __syncthreads();                          // all h_lds reads complete
        float S = __fadd_rn(x, dS);               // S = x + h@W_rec.T
        float z = __fadd_rn(S, dA);               // S + h@W_adapt.T
        float sig = xla_sigmoid(z);               // 1/(1+exp(-z)), Cephes exp
        float tvc = f32clip(__fmul_rn(tau_i, sig), 1e-6f, 1e6f);
        float kk = __fsub_rn(S, hcur) / tvc;      // separate sub, IEEE div
        if (st == 0) {
          acc = kk;
          hcur = __fadd_rn(h, __fmul_rn(0.005f, kk));
        } else if (st == 1) {
          acc = __fadd_rn(acc, __fmul_rn(2.f, kk));
          hcur = __fadd_rn(h, __fmul_rn(0.005f, kk));
        } else if (st == 2) {
          acc = __fadd_rn(acc, __fmul_rn(2.f, kk));
          hcur = __fadd_rn(h, __fmul_rn(0.01f, kk));
        } else {
          acc = __fadd_rn(acc, kk);
          float dl = f32clip(__fmul_rn(acc, C_DT6), -1e6f, 1e6f);
          h = __fadd_rn(h, dl);
          hcur = h;
        }
        h_lds[i] = hcur;
        __syncthreads();                          // new state visible
      }
    }
    h_hist[(b * Tn + t) * Hn + i] = h;
  }
}

// out[b,t,o] = (ascending fmaf chain) h.W_out[o,:], then + b_out[o]
__global__ __launch_bounds__(128) void k_out(const float* __restrict__ h_hist,
                                             const float* __restrict__ W_outT,
                                             const float* __restrict__ b_out,
                                             float* __restrict__ outp) {
  __shared__ float hs[Hn];
  int bt = blockIdx.x, o = threadIdx.x;
  hs[o] = h_hist[bt * Hn + o];
  hs[o + 128] = h_hist[bt * Hn + o + 128];
  __syncthreads();
  float d = 0.f;
  #pragma unroll
  for (int j = 0; j < Hn; ++j)
    d = __builtin_fmaf(hs[j], W_outT[j * OUTn + o], d);
  outp[bt * OUTn + o] = __fadd_rn(d, b_out[o]);
}

extern "C" void kernel_launch(void* const* d_in, const int* in_sizes, int n_in,
                              void* d_out, int out_size, void* d_ws, size_t ws_size,
                              hipStream_t stream) {
  const float* x       = (const float*)d_in[0];
  const float* W_in    = (const float*)d_in[1];
  const float* b_in    = (const float*)d_in[2];
  const float* W_rec   = (const float*)d_in[3];
  const float* W_adapt = (const float*)d_in[4];
  const float* W_out   = (const float*)d_in[5];
  const float* b_out   = (const float*)d_in[6];
  const float* tau     = (const float*)d_in[7];
  float* outp = (float*)d_out;
  float* ws = (float*)d_ws;

  float* W_inT   = ws;                 // 32768
  float* W_outT  = ws + 32768;         // 32768
  float* W_recT  = ws + 65536;         // 65536
  float* W_adaptT= ws + 131072;        // 65536
  float* emb     = ws + 196608;        // 1048576
  float* h_hist  = ws + 1245184;       // 1048576  (end 2293760 floats ~9.2MB)

  (void)in_sizes; (void)n_in; (void)out_size; (void)ws_size;

  k_prep<<<768, 256, 0, stream>>>(W_in, W_out, W_rec, W_adapt,
                                  W_inT, W_outT, W_recT, W_adaptT);
  k_embed<<<Bn * Tn, 256, 0, stream>>>(x, W_inT, b_in, emb);
  k_ltc<<<Bn, 256, 0, stream>>>(W_recT, W_adaptT, tau, emb, h_hist);
  k_out<<<Bn * Tn, 128, 0, stream>>>(h_hist, W_outT, b_out, outp);
}

// Round 13
// 5593.191 us; speedup vs baseline: 1.9811x; 1.9811x over previous
//
#include <hip/hip_runtime.h>
#include <math.h>

#pragma clang fp contract(off)

// LTC network: B=32, T=128, IN=128, H=256, OUT=5x4 RK4 stages/t, dt=0.01
// Round 13: bit-exact arithmetic (absmax 0.0 since R9). Perf redesign around
// the measured bottleneck (weights streamed from L2 at ~64 B/cy/CU ≈ 8000
// cy/stage in R9-R12):
//  - FULL WEIGHT RESIDENCY: 512 thr role-split; per chain w[0..191] in VGPRs
//    (waves_per_eu(2,2) -> 256-VGPR budget, proven to move allocator in R12)
//    + w[192..255] in LDS float4 bundles [16][512] (128 KB). No streaming.
//  - h distribution via v_readlane: 4 conflict-free b32 loads pack h into 4
//    lane-regs; chain reads h_j as SGPR via __builtin_amdgcn_readlane with
//    compile-time lane index -> feeds v_fmac directly. DS traffic per stage:
//    20 instr/thread vs 64 broadcasts. Same bits, same ascending fmaf order.
//  - st-loop not unrolled (I$: body ~10 KB).
// Numerics (DO NOT TOUCH — bit-exact vs XLA-CPU golden):
//  dots: ascending-k __builtin_fmaf chain from 0.0; x/bias added after,
//  unfused; sigmoid = 1/(1+CephesExp(-z)) per GenerateVF32Exp; unfused RK4
//  elementwise; fp contract off file-wide.

#define Bn 32
#define Tn 128
#define INn 128
#define Hn 256
#define OUTn 128
#define NSTEPS 5

__device__ __forceinline__ float f32clip(float x, float lo, float hi) {
  float y = (x >= lo) ? x : lo;
  y = (y <= hi) ? y : hi;
  return (x == x) ? y : x;    // NaN propagates (safety; none occur)
}

// XLA CPU GenerateVF32Exp (Cephes expf), bit-exact reconstruction.
__device__ __forceinline__ float xla_expf(float x) {
  x = fminf(x, 88.3762626647950f);         // clamp high
  x = fmaxf(x, -88.3762626647949f);        // clamp low
  float fx = floorf(__builtin_fmaf(x, 1.44269504088896341f, 0.5f)); // fused
  float tmp = __fmul_rn(0.693359375f, fx);         // unfused Cody-Waite hi
  float z  = __fmul_rn(-2.12194440e-4f, fx);       // unfused Cody-Waite lo
  float r  = __fsub_rn(x, tmp);
  r = __fsub_rn(r, z);
  float r2 = __fmul_rn(r, r);
  float y = __builtin_fmaf(r, 1.9875691500e-4f, 1.3981999507e-3f);  // MulAdd
  y = __builtin_fmaf(y, r, 8.3334519073e-3f);
  y = __builtin_fmaf(y, r, 4.1665795894e-2f);
  y = __builtin_fmaf(y, r, 1.6666665459e-1f);
  y = __builtin_fmaf(y, r, 5.0000001201e-1f);
  y = __builtin_fmaf(y, r2, r);
  y = __fadd_rn(1.0f, y);
  int m = (int)fx;                          // FPToSI (fx integral)
  float s = __int_as_float((m + 127) << 23);
  return __fmul_rn(y, s);
}

// LogisticExpander: 1 / (1 + exp(-z))
__device__ __forceinline__ float xla_sigmoid(float zin) {
  float e = xla_expf(-zin);
  return 1.0f / __fadd_rn(1.0f, e);        // IEEE f32 div
}

__device__ __forceinline__ float rdlane(float v, int l) {
  return __int_as_float(__builtin_amdgcn_readlane(__float_as_int(v), l));
}

__global__ __launch_bounds__(256) void k_prep(const float* __restrict__ W_in,
                                              const float* __restrict__ W_out,
                                              const float* __restrict__ W_rec,
                                              const float* __restrict__ W_adapt,
                                              float* __restrict__ W_inT,
                                              float* __restrict__ W_outT,
                                              float* __restrict__ W_recT,
                                              float* __restrict__ W_adaptT) {
  int idx = blockIdx.x * 256 + threadIdx.x;     // 768*256 = 196608
  if (idx < 32768) {            // W_in [256][128] -> W_inT[j][h]
    int h = idx >> 7, j = idx & 127;
    W_inT[j * Hn + h] = W_in[idx];
  } else if (idx < 65536) {     // W_out [128][256] -> W_outT[i][o]
    int k = idx - 32768; int o = k >> 8, i = k & 255;
    W_outT[i * OUTn + o] = W_out[k];
  } else if (idx < 131072) {    // W_rec [256][256] -> W_recT[c][r]
    int k = idx - 65536; int r = k >> 8, c = k & 255;
    W_recT[c * Hn + r] = W_rec[k];
  } else {                      // W_adapt -> W_adaptT[c][r]
    int k = idx - 131072; int r = k >> 8, c = k & 255;
    W_adaptT[c * Hn + r] = W_adapt[k];
  }
}

// emb[b,t,h] = (ascending-i fmaf chain, Eigen) x[b,t,:].W_in[h,:], then + b_in
__global__ __launch_bounds__(256) void k_embed(const float* __restrict__ xin,
                                               const float* __restrict__ W_inT,
                                               const float* __restrict__ b_in,
                                               float* __restrict__ emb) {
  __shared__ float xs[INn];
  int bt = blockIdx.x, h = threadIdx.x;
  if (h < INn) xs[h] = xin[bt * INn + h];
  __syncthreads();
  float d = 0.f;
  #pragma unroll
  for (int j = 0; j < INn; ++j)
    d = __builtin_fmaf(xs[j], W_inT[j * Hn + h], d);  // Eigen gebp chain
  emb[bt * Hn + h] = __fadd_rn(d, b_in[h]);           // + b_in separate op
}

__global__ __launch_bounds__(512)
__attribute__((amdgpu_waves_per_eu(2, 2)))
void k_ltc(const float* __restrict__ W_recT,
           const float* __restrict__ W_adaptT,
           const float* __restrict__ tau,
           const float* __restrict__ emb,
           float* __restrict__ h_hist) {
  const int b = blockIdx.x;
  const int tid = threadIdx.x;
  const int role = tid >> 8;     // 0: S-chain (W_rec) + elementwise; 1: A-chain
  const int i = tid & 255;
  const int lane = tid & 63;

  __shared__ __align__(16) float h_lds[Hn];        // 1 KB
  __shared__ float partA[Hn];                      // 1 KB
  __shared__ __align__(16) float4 wlds[16][512];   // 128 KB: j=192..255 bundles

  const float* WT = role ? W_adaptT : W_recT;
  float w[192];
  #pragma unroll
  for (int m = 0; m < 192; ++m) w[m] = WT[m * Hn + i];   // coalesced one-time
  #pragma unroll
  for (int m = 0; m < 192; ++m) asm volatile("" : "+v"(w[m]));  // pin in VGPRs
  #pragma unroll
  for (int r4 = 0; r4 < 16; ++r4) {                // j = 192..255 into LDS
    float4 v;
    v.x = WT[(192 + 4*r4 + 0) * Hn + i];
    v.y = WT[(192 + 4*r4 + 1) * Hn + i];
    v.z = WT[(192 + 4*r4 + 2) * Hn + i];
    v.w = WT[(192 + 4*r4 + 3) * Hn + i];
    wlds[r4][tid] = v;
  }
  const float tau_i = tau[i];
  const float C_DT6 = (float)(0.01 / 6.0);  // f32(DT/6.0), weak-scalar cast
  float h = 0.f, hcur = 0.f, acc = 0.f;
  if (role == 0) h_lds[i] = 0.f;
  __syncthreads();

  #pragma unroll 1
  for (int t = 0; t < Tn; ++t) {
    const float x = (role == 0) ? emb[(b * Tn + t) * Hn + i] : 0.f;
    #pragma unroll 1
    for (int s = 0; s < NSTEPS; ++s) {
      #pragma unroll 1
      for (int st = 0; st < 4; ++st) {
        // pack current state into 4 lane-regs (conflict-free b32 reads)
        const float vh0 = h_lds[lane];
        const float vh1 = h_lds[64 + lane];
        const float vh2 = h_lds[128 + lane];
        const float vh3 = h_lds[192 + lane];
        // dot: ascending-j fmaf chain from 0 (Eigen gebp per-element chain);
        // h_j delivered via readlane (SGPR) -> identical bits & order.
        float d = 0.f;
        #pragma unroll
        for (int j = 0; j < 64; ++j)
          d = __builtin_fmaf(rdlane(vh0, j), w[j], d);
        #pragma unroll
        for (int j = 0; j < 64; ++j)
          d = __builtin_fmaf(rdlane(vh1, j), w[64 + j], d);
        #pragma unroll
        for (int j = 0; j < 64; ++j)
          d = __builtin_fmaf(rdlane(vh2, j), w[128 + j], d);
        #pragma unroll
        for (int r4 = 0; r4 < 16; ++r4) {          // j = 192..255 from LDS
          const float4 wb = wlds[r4][tid];
          d = __builtin_fmaf(rdlane(vh3, 4*r4 + 0), wb.x, d);
          d = __builtin_fmaf(rdlane(vh3, 4*r4 + 1), wb.y, d);
          d = __builtin_fmaf(rdlane(vh3, 4*r4 + 2), wb.z, d);
          d = __builtin_fmaf(rdlane(vh3, 4*r4 + 3), wb.w, d);
        }
        if (role == 1) partA[i] = d;
        __syncthreads();
        if (role == 0) {
          float S = __fadd_rn(x, d);              // S = x + h@W_rec.T
          float z = __fadd_rn(S, partA[i]);       // S + h@W_adapt.T
          float sig = xla_sigmoid(z);             // 1/(1+exp(-z)), Cephes exp
          float tvc = f32clip(__fmul_rn(tau_i, sig), 1e-6f, 1e6f);
          float kk = __fsub_rn(S, hcur) / tvc;    // separate sub, IEEE div
          if (st == 0) {
            acc = kk;
            hcur = __fadd_rn(h, __fmul_rn(0.005f, kk));
          } else if (st == 1) {
            acc = __fadd_rn(acc, __fmul_rn(2.f, kk));
            hcur = __fadd_rn(h, __fmul_rn(0.005f, kk));
          } else if (st == 2) {
            acc = __fadd_rn(acc, __fmul_rn(2.f, kk));
            hcur = __fadd_rn(h, __fmul_rn(0.01f, kk));
          } else {
            acc = __fadd_rn(acc, kk);
            float dl = f32clip(__fmul_rn(acc, C_DT6), -1e6f, 1e6f);
            h = __fadd_rn(h, dl);
            hcur = h;
          }
          h_lds[i] = hcur;
        }
        __syncthreads();
      }
    }
    if (role == 0) h_hist[(b * Tn + t) * Hn + i] = h;
  }
}

// out[b,t,o] = (ascending fmaf chain) h.W_out[o,:], then + b_out[o]
__global__ __launch_bounds__(128) void k_out(const float* __restrict__ h_hist,
                                             const float* __restrict__ W_outT,
                                             const float* __restrict__ b_out,
                                             float* __restrict__ outp) {
  __shared__ float hs[Hn];
  int bt = blockIdx.x, o = threadIdx.x;
  hs[o] = h_hist[bt * Hn + o];
  hs[o + 128] = h_hist[bt * Hn + o + 128];
  __syncthreads();
  float d = 0.f;
  #pragma unroll
  for (int j = 0; j < Hn; ++j)
    d = __builtin_fmaf(hs[j], W_outT[j * OUTn + o], d);
  outp[bt * OUTn + o] = __fadd_rn(d, b_out[o]);
}

extern "C" void kernel_launch(void* const* d_in, const int* in_sizes, int n_in,
                              void* d_out, int out_size, void* d_ws, size_t ws_size,
                              hipStream_t stream) {
  const float* x       = (const float*)d_in[0];
  const float* W_in    = (const float*)d_in[1];
  const float* b_in    = (const float*)d_in[2];
  const float* W_rec   = (const float*)d_in[3];
  const float* W_adapt = (const float*)d_in[4];
  const float* W_out   = (const float*)d_in[5];
  const float* b_out   = (const float*)d_in[6];
  const float* tau     = (const float*)d_in[7];
  float* outp = (float*)d_out;
  float* ws = (float*)d_ws;

  float* W_inT   = ws;                 // 32768
  float* W_outT  = ws + 32768;         // 32768
  float* W_recT  = ws + 65536;         // 65536
  float* W_adaptT= ws + 131072;        // 65536
  float* emb     = ws + 196608;        // 1048576
  float* h_hist  = ws + 1245184;       // 1048576  (end 2293760 floats ~9.2MB)

  (void)in_sizes; (void)n_in; (void)out_size; (void)ws_size;

  k_prep<<<768, 256, 0, stream>>>(W_in, W_out, W_rec, W_adapt,
                                  W_inT, W_outT, W_recT, W_adaptT);
  k_embed<<<Bn * Tn, 256, 0, stream>>>(x, W_inT, b_in, emb);
  k_ltc<<<Bn, 512, 0, stream>>>(W_recT, W_adaptT, tau, emb, h_hist);
  k_out<<<Bn * Tn, 128, 0, stream>>>(h_hist, W_outT, b_out, outp);
}

// Round 14
// 5592.207 us; speedup vs baseline: 1.9815x; 1.0002x over previous
//
#include <hip/hip_runtime.h>
#include <math.h>

#pragma clang fp contract(off)

// LTC network: B=32, T=128, IN=128, H=256, OUT=128, 5 RK4 steps/t, dt=0.01
// Round 14: bit-exact arithmetic (absmax 0.0 since R9). Single lever vs R13:
//  amdgpu_waves_per_eu(1,2) — min=1 raises allocator budget to the full
//  512-reg/SIMD file so w[192]+working (~232) fits ARCH VGPRs; R13's (2,2)
//  budgeted 256 -> arch 128 + ~100 AGPR spills (v_accvgpr_read per MAC use =
//  the measured extra issue: 5200cy/stage at 83% per-CU VALUBusy).
//  HW still runs 2 waves/SIMD (2x232 <= 512 regs/SIMD).
// Numerics (DO NOT TOUCH — bit-exact vs XLA-CPU golden):
//  dots: ascending-k __builtin_fmaf chain from 0.0; x/bias added after,
//  unfused; sigmoid = 1/(1+CephesExp(-z)) per GenerateVF32Exp; unfused RK4
//  elementwise; fp contract off file-wide; h via v_readlane (bit-exact,
//  verified R13).

#define Bn 32
#define Tn 128
#define INn 128
#define Hn 256
#define OUTn 128
#define NSTEPS 5

__device__ __forceinline__ float f32clip(float x, float lo, float hi) {
  float y = (x >= lo) ? x : lo;
  y = (y <= hi) ? y : hi;
  return (x == x) ? y : x;    // NaN propagates (safety; none occur)
}

// XLA CPU GenerateVF32Exp (Cephes expf), bit-exact reconstruction.
__device__ __forceinline__ float xla_expf(float x) {
  x = fminf(x, 88.3762626647950f);         // clamp high
  x = fmaxf(x, -88.3762626647949f);        // clamp low
  float fx = floorf(__builtin_fmaf(x, 1.44269504088896341f, 0.5f)); // fused
  float tmp = __fmul_rn(0.693359375f, fx);         // unfused Cody-Waite hi
  float z  = __fmul_rn(-2.12194440e-4f, fx);       // unfused Cody-Waite lo
  float r  = __fsub_rn(x, tmp);
  r = __fsub_rn(r, z);
  float r2 = __fmul_rn(r, r);
  float y = __builtin_fmaf(r, 1.9875691500e-4f, 1.3981999507e-3f);  // MulAdd
  y = __builtin_fmaf(y, r, 8.3334519073e-3f);
  y = __builtin_fmaf(y, r, 4.1665795894e-2f);
  y = __builtin_fmaf(y, r, 1.6666665459e-1f);
  y = __builtin_fmaf(y, r, 5.0000001201e-1f);
  y = __builtin_fmaf(y, r2, r);
  y = __fadd_rn(1.0f, y);
  int m = (int)fx;                          // FPToSI (fx integral)
  float s = __int_as_float((m + 127) << 23);
  return __fmul_rn(y, s);
}

// LogisticExpander: 1 / (1 + exp(-z))
__device__ __forceinline__ float xla_sigmoid(float zin) {
  float e = xla_expf(-zin);
  return 1.0f / __fadd_rn(1.0f, e);        // IEEE f32 div
}

__device__ __forceinline__ float rdlane(float v, int l) {
  return __int_as_float(__builtin_amdgcn_readlane(__float_as_int(v), l));
}

__global__ __launch_bounds__(256) void k_prep(const float* __restrict__ W_in,
                                              const float* __restrict__ W_out,
                                              const float* __restrict__ W_rec,
                                              const float* __restrict__ W_adapt,
                                              float* __restrict__ W_inT,
                                              float* __restrict__ W_outT,
                                              float* __restrict__ W_recT,
                                              float* __restrict__ W_adaptT) {
  int idx = blockIdx.x * 256 + threadIdx.x;     // 768*256 = 196608
  if (idx < 32768) {            // W_in [256][128] -> W_inT[j][h]
    int h = idx >> 7, j = idx & 127;
    W_inT[j * Hn + h] = W_in[idx];
  } else if (idx < 65536) {     // W_out [128][256] -> W_outT[i][o]
    int k = idx - 32768; int o = k >> 8, i = k & 255;
    W_outT[i * OUTn + o] = W_out[k];
  } else if (idx < 131072) {    // W_rec [256][256] -> W_recT[c][r]
    int k = idx - 65536; int r = k >> 8, c = k & 255;
    W_recT[c * Hn + r] = W_rec[k];
  } else {                      // W_adapt -> W_adaptT[c][r]
    int k = idx - 131072; int r = k >> 8, c = k & 255;
    W_adaptT[c * Hn + r] = W_adapt[k];
  }
}

// emb[b,t,h] = (ascending-i fmaf chain, Eigen) x[b,t,:].W_in[h,:], then + b_in
__global__ __launch_bounds__(256) void k_embed(const float* __restrict__ xin,
                                               const float* __restrict__ W_inT,
                                               const float* __restrict__ b_in,
                                               float* __restrict__ emb) {
  __shared__ float xs[INn];
  int bt = blockIdx.x, h = threadIdx.x;
  if (h < INn) xs[h] = xin[bt * INn + h];
  __syncthreads();
  float d = 0.f;
  #pragma unroll
  for (int j = 0; j < INn; ++j)
    d = __builtin_fmaf(xs[j], W_inT[j * Hn + h], d);  // Eigen gebp chain
  emb[bt * Hn + h] = __fadd_rn(d, b_in[h]);           // + b_in separate op
}

__global__ __launch_bounds__(512)
__attribute__((amdgpu_waves_per_eu(1, 2)))
void k_ltc(const float* __restrict__ W_recT,
           const float* __restrict__ W_adaptT,
           const float* __restrict__ tau,
           const float* __restrict__ emb,
           float* __restrict__ h_hist) {
  const int b = blockIdx.x;
  const int tid = threadIdx.x;
  const int role = tid >> 8;     // 0: S-chain (W_rec) + elementwise; 1: A-chain
  const int i = tid & 255;
  const int lane = tid & 63;

  __shared__ __align__(16) float h_lds[Hn];        // 1 KB
  __shared__ float partA[Hn];                      // 1 KB
  __shared__ __align__(16) float4 wlds[16][512];   // 128 KB: j=192..255 bundles

  const float* WT = role ? W_adaptT : W_recT;
  float w[192];
  #pragma unroll
  for (int m = 0; m < 192; ++m) w[m] = WT[m * Hn + i];   // coalesced one-time
  #pragma unroll
  for (int m = 0; m < 192; ++m) asm volatile("" : "+v"(w[m]));  // pin in VGPRs
  #pragma unroll
  for (int r4 = 0; r4 < 16; ++r4) {                // j = 192..255 into LDS
    float4 v;
    v.x = WT[(192 + 4*r4 + 0) * Hn + i];
    v.y = WT[(192 + 4*r4 + 1) * Hn + i];
    v.z = WT[(192 + 4*r4 + 2) * Hn + i];
    v.w = WT[(192 + 4*r4 + 3) * Hn + i];
    wlds[r4][tid] = v;
  }
  const float tau_i = tau[i];
  const float C_DT6 = (float)(0.01 / 6.0);  // f32(DT/6.0), weak-scalar cast
  float h = 0.f, hcur = 0.f, acc = 0.f;
  if (role == 0) h_lds[i] = 0.f;
  __syncthreads();

  #pragma unroll 1
  for (int t = 0; t < Tn; ++t) {
    const float x = (role == 0) ? emb[(b * Tn + t) * Hn + i] : 0.f;
    #pragma unroll 1
    for (int s = 0; s < NSTEPS; ++s) {
      #pragma unroll 1
      for (int st = 0; st < 4; ++st) {
        // pack current state into 4 lane-regs (conflict-free b32 reads)
        const float vh0 = h_lds[lane];
        const float vh1 = h_lds[64 + lane];
        const float vh2 = h_lds[128 + lane];
        const float vh3 = h_lds[192 + lane];
        // dot: ascending-j fmaf chain from 0 (Eigen gebp per-element chain);
        // h_j delivered via readlane (SGPR) -> identical bits & order.
        float d = 0.f;
        #pragma unroll
        for (int j = 0; j < 64; ++j)
          d = __builtin_fmaf(rdlane(vh0, j), w[j], d);
        #pragma unroll
        for (int j = 0; j < 64; ++j)
          d = __builtin_fmaf(rdlane(vh1, j), w[64 + j], d);
        #pragma unroll
        for (int j = 0; j < 64; ++j)
          d = __builtin_fmaf(rdlane(vh2, j), w[128 + j], d);
        #pragma unroll
        for (int r4 = 0; r4 < 16; ++r4) {          // j = 192..255 from LDS
          const float4 wb = wlds[r4][tid];
          d = __builtin_fmaf(rdlane(vh3, 4*r4 + 0), wb.x, d);
          d = __builtin_fmaf(rdlane(vh3, 4*r4 + 1), wb.y, d);
          d = __builtin_fmaf(rdlane(vh3, 4*r4 + 2), wb.z, d);
          d = __builtin_fmaf(rdlane(vh3, 4*r4 + 3), wb.w, d);
        }
        if (role == 1) partA[i] = d;
        __syncthreads();
        if (role == 0) {
          float S = __fadd_rn(x, d);              // S = x + h@W_rec.T
          float z = __fadd_rn(S, partA[i]);       // S + h@W_adapt.T
          float sig = xla_sigmoid(z);             // 1/(1+exp(-z)), Cephes exp
          float tvc = f32clip(__fmul_rn(tau_i, sig), 1e-6f, 1e6f);
          float kk = __fsub_rn(S, hcur) / tvc;    // separate sub, IEEE div
          if (st == 0) {
            acc = kk;
            hcur = __fadd_rn(h, __fmul_rn(0.005f, kk));
          } else if (st == 1) {
            acc = __fadd_rn(acc, __fmul_rn(2.f, kk));
            hcur = __fadd_rn(h, __fmul_rn(0.005f, kk));
          } else if (st == 2) {
            acc = __fadd_rn(acc, __fmul_rn(2.f, kk));
            hcur = __fadd_rn(h, __fmul_rn(0.01f, kk));
          } else {
            acc = __fadd_rn(acc, kk);
            float dl = f32clip(__fmul_rn(acc, C_DT6), -1e6f, 1e6f);
            h = __fadd_rn(h, dl);
            hcur = h;
          }
          h_lds[i] = hcur;
        }
        __syncthreads();
      }
    }
    if (role == 0) h_hist[(b * Tn + t) * Hn + i] = h;
  }
}

// out[b,t,o] = (ascending fmaf chain) h.W_out[o,:], then + b_out[o]
__global__ __launch_bounds__(128) void k_out(const float* __restrict__ h_hist,
                                             const float* __restrict__ W_outT,
                                             const float* __restrict__ b_out,
                                             float* __restrict__ outp) {
  __shared__ float hs[Hn];
  int bt = blockIdx.x, o = threadIdx.x;
  hs[o] = h_hist[bt * Hn + o];
  hs[o + 128] = h_hist[bt * Hn + o + 128];
  __syncthreads();
  float d = 0.f;
  #pragma unroll
  for (int j = 0; j < Hn; ++j)
    d = __builtin_fmaf(hs[j], W_outT[j * OUTn + o], d);
  outp[bt * OUTn + o] = __fadd_rn(d, b_out[o]);
}

extern "C" void kernel_launch(void* const* d_in, const int* in_sizes, int n_in,
                              void* d_out, int out_size, void* d_ws, size_t ws_size,
                              hipStream_t stream) {
  const float* x       = (const float*)d_in[0];
  const float* W_in    = (const float*)d_in[1];
  const float* b_in    = (const float*)d_in[2];
  const float* W_rec   = (const float*)d_in[3];
  const float* W_adapt = (const float*)d_in[4];
  const float* W_out   = (const float*)d_in[5];
  const float* b_out   = (const float*)d_in[6];
  const float* tau     = (const float*)d_in[7];
  float* outp = (float*)d_out;
  float* ws = (float*)d_ws;

  float* W_inT   = ws;                 // 32768
  float* W_outT  = ws + 32768;         // 32768
  float* W_recT  = ws + 65536;         // 65536
  float* W_adaptT= ws + 131072;        // 65536
  float* emb     = ws + 196608;        // 1048576
  float* h_hist  = ws + 1245184;       // 1048576  (end 2293760 floats ~9.2MB)

  (void)in_sizes; (void)n_in; (void)out_size; (void)ws_size;

  k_prep<<<768, 256, 0, stream>>>(W_in, W_out, W_rec, W_adapt,
                                  W_inT, W_outT, W_recT, W_adaptT);
  k_embed<<<Bn * Tn, 256, 0, stream>>>(x, W_inT, b_in, emb);
  k_ltc<<<Bn, 512, 0, stream>>>(W_recT, W_adaptT, tau, emb, h_hist);
  k_out<<<Bn * Tn, 128, 0, stream>>>(h_hist, W_outT, b_out, outp);
}